// Round 4
// baseline (966.850 us; speedup 1.0000x reference)
//
#include <hip/hip_runtime.h>
#include <math.h>

// LightGCN propagation, round 4.
// - Features and intermediates in bf16 (f32 math): halves gather volume.
// - CSR build: cursor pre-initialized to offs -> fill is one atomic + one
//   store per entry, 2 edges per thread for 4 independent chains.
// - Single fused epilogue computes out = orig + h1 + h2/2 + l2norm(g3)/3.

__device__ __forceinline__ unsigned short f2bf(float f) {
    unsigned int b = __float_as_uint(f);
    b += 0x7FFFu + ((b >> 16) & 1u);          // round-to-nearest-even
    return (unsigned short)(b >> 16);
}
__device__ __forceinline__ float bf2f(unsigned short u) {
    return __uint_as_float(((unsigned int)u) << 16);
}

__global__ void conv_bf16_kernel(const float* __restrict__ src,
                                 unsigned short* __restrict__ dst, int n4) {
    int t = blockIdx.x * blockDim.x + threadIdx.x;
    if (t >= n4) return;
    float4 f = ((const float4*)src)[t];
    ushort4 o;
    o.x = f2bf(f.x); o.y = f2bf(f.y); o.z = f2bf(f.z); o.w = f2bf(f.w);
    ((ushort4*)dst)[t] = o;
}

__global__ void count_deg_kernel(const int* __restrict__ eu, const int* __restrict__ ei,
                                 int* __restrict__ deg, int E, int NU) {
    int t = blockIdx.x * blockDim.x + threadIdx.x;
    int e0 = t * 2;
    if (e0 >= E) return;
    if (e0 + 1 < E) {
        int2 u = *(const int2*)(eu + e0);
        int2 i = *(const int2*)(ei + e0);
        atomicAdd(&deg[u.x], 1); atomicAdd(&deg[u.y], 1);
        atomicAdd(&deg[NU + i.x], 1); atomicAdd(&deg[NU + i.y], 1);
    } else {
        atomicAdd(&deg[eu[e0]], 1);
        atomicAdd(&deg[NU + ei[e0]], 1);
    }
}

__global__ void bump_kernel(const int* __restrict__ deg, int* __restrict__ offs,
                            int* __restrict__ cursor, int* __restrict__ total, int n) {
    int i = blockIdx.x * blockDim.x + threadIdx.x;
    if (i >= n) return;
    int o = atomicAdd(total, deg[i]);   // bump alloc; row order irrelevant
    offs[i] = o;
    cursor[i] = o;                      // fill uses cursor directly
}

__global__ void fill_csr_kernel(const int* __restrict__ eu, const int* __restrict__ ei,
                                int* __restrict__ cursor, int* __restrict__ csr,
                                int E, int NU) {
    int t = blockIdx.x * blockDim.x + threadIdx.x;
    int e0 = t * 2;
    if (e0 >= E) return;
    if (e0 + 1 < E) {
        int2 u = *(const int2*)(eu + e0);
        int2 i = *(const int2*)(ei + e0);
        int s0 = atomicAdd(&cursor[u.x], 1);
        int s1 = atomicAdd(&cursor[u.y], 1);
        int s2 = atomicAdd(&cursor[NU + i.x], 1);
        int s3 = atomicAdd(&cursor[NU + i.y], 1);
        csr[s0] = i.x; csr[s1] = i.y;   // user rows hold item srcs
        csr[s2] = u.x; csr[s3] = u.y;   // item rows hold user srcs
    } else {
        int u = eu[e0], i = ei[e0];
        csr[atomicAdd(&cursor[u], 1)] = i;
        csr[atomicAdd(&cursor[NU + i], 1)] = u;
    }
}

// l2-normalized weighted sum for one dest row; 4 groups of 16 lanes walk
// 4 interleaved edge streams (unroll x2 => 8 gathers in flight per wave).
__device__ __forceinline__ float4 gather_row(const unsigned short* __restrict__ sfeat,
                                             const int* __restrict__ deg,
                                             const int* __restrict__ csr,
                                             int start, int dcount, int sdb,
                                             int g, int l16) {
    float degr = (float)dcount;
    float4 a0 = make_float4(0.f, 0.f, 0.f, 0.f);
    float4 a1 = make_float4(0.f, 0.f, 0.f, 0.f);
    int j = g;
    for (; j + 4 < dcount; j += 8) {
        int s0 = csr[start + j];
        int s1 = csr[start + j + 4];
        float w0 = rsqrtf(degr * (float)deg[sdb + s0]);
        float w1 = rsqrtf(degr * (float)deg[sdb + s1]);
        ushort4 f0 = *(const ushort4*)(sfeat + (size_t)s0 * 64 + l16 * 4);
        ushort4 f1 = *(const ushort4*)(sfeat + (size_t)s1 * 64 + l16 * 4);
        a0.x = fmaf(w0, bf2f(f0.x), a0.x); a0.y = fmaf(w0, bf2f(f0.y), a0.y);
        a0.z = fmaf(w0, bf2f(f0.z), a0.z); a0.w = fmaf(w0, bf2f(f0.w), a0.w);
        a1.x = fmaf(w1, bf2f(f1.x), a1.x); a1.y = fmaf(w1, bf2f(f1.y), a1.y);
        a1.z = fmaf(w1, bf2f(f1.z), a1.z); a1.w = fmaf(w1, bf2f(f1.w), a1.w);
    }
    if (j < dcount) {
        int s0 = csr[start + j];
        float w0 = rsqrtf(degr * (float)deg[sdb + s0]);
        ushort4 f0 = *(const ushort4*)(sfeat + (size_t)s0 * 64 + l16 * 4);
        a0.x = fmaf(w0, bf2f(f0.x), a0.x); a0.y = fmaf(w0, bf2f(f0.y), a0.y);
        a0.z = fmaf(w0, bf2f(f0.z), a0.z); a0.w = fmaf(w0, bf2f(f0.w), a0.w);
    }
    float4 a = make_float4(a0.x + a1.x, a0.y + a1.y, a0.z + a1.z, a0.w + a1.w);
    #pragma unroll
    for (int m = 16; m <= 32; m <<= 1) {
        a.x += __shfl_xor(a.x, m, 64);
        a.y += __shfl_xor(a.y, m, 64);
        a.z += __shfl_xor(a.z, m, 64);
        a.w += __shfl_xor(a.w, m, 64);
    }
    float ss = a.x * a.x + a.y * a.y + a.z * a.z + a.w * a.w;
    #pragma unroll
    for (int m = 1; m <= 8; m <<= 1) ss += __shfl_xor(ss, m, 64);
    float scale = 1.f / fmaxf(sqrtf(ss), 1e-12f);
    a.x *= scale; a.y *= scale; a.z *= scale; a.w *= scale;
    return a;
}

// Rows [0,NU): users (gather from items); rows [NU,NT): items (from users).
__global__ void prop_both_kernel(const unsigned short* __restrict__ uc,
                                 const unsigned short* __restrict__ ic,
                                 unsigned short* __restrict__ ud,
                                 unsigned short* __restrict__ id,
                                 const int* __restrict__ offs, const int* __restrict__ deg,
                                 const int* __restrict__ csr, int NU, int NT) {
    int wave = blockIdx.x * (blockDim.x >> 6) + (threadIdx.x >> 6);
    if (wave >= NT) return;
    int lane = threadIdx.x & 63;
    int g = lane >> 4, l16 = lane & 15;
    int r = __builtin_amdgcn_readfirstlane(wave);
    const unsigned short* sfeat;
    unsigned short* dst;
    int sdb;
    if (r < NU) { sfeat = ic; dst = ud + (size_t)r * 64; sdb = NU; }
    else        { sfeat = uc; dst = id + (size_t)(r - NU) * 64; sdb = 0; }
    int start  = __builtin_amdgcn_readfirstlane(offs[r]);
    int dcount = __builtin_amdgcn_readfirstlane(deg[r]);
    float4 a = gather_row(sfeat, deg, csr, start, dcount, sdb, g, l16);
    if (g == 0) {
        ushort4 o;
        o.x = f2bf(a.x); o.y = f2bf(a.y); o.z = f2bf(a.z); o.w = f2bf(a.w);
        *(ushort4*)(dst + l16 * 4) = o;
    }
}

// Fused epilogue: out = orig + h1 + 0.5*h2 + (1/3)*l2norm(layer-3 gather).
__global__ void final_kernel(const float* __restrict__ user_feat,
                             const float* __restrict__ item_feat,
                             const unsigned short* __restrict__ uhA,
                             const unsigned short* __restrict__ ihA,
                             const unsigned short* __restrict__ uhB,
                             const unsigned short* __restrict__ ihB,
                             const int* __restrict__ users, const int* __restrict__ pos,
                             const int* __restrict__ neg,
                             const int* __restrict__ offs, const int* __restrict__ deg,
                             const int* __restrict__ csr, float* __restrict__ out,
                             int NU, int B) {
    int wave = blockIdx.x * (blockDim.x >> 6) + (threadIdx.x >> 6);
    if (wave >= 3 * B) return;
    int lane = threadIdx.x & 63;
    int g = lane >> 4, l16 = lane & 15;
    int seg = wave / B, b = wave - seg * B;
    int r, idx, sdb;
    const unsigned short *sfeat, *h1, *h2;
    const float* orig;
    if (seg == 0) { idx = users[b]; r = idx;      sfeat = ihB; sdb = NU; orig = user_feat; h1 = uhA; h2 = uhB; }
    else {
        idx = (seg == 1) ? pos[b] : neg[b];
        r = NU + idx; sfeat = uhB; sdb = 0; orig = item_feat; h1 = ihA; h2 = ihB;
    }
    r = __builtin_amdgcn_readfirstlane(r);
    int start  = __builtin_amdgcn_readfirstlane(offs[r]);
    int dcount = __builtin_amdgcn_readfirstlane(deg[r]);
    float4 a = gather_row(sfeat, deg, csr, start, dcount, sdb, g, l16);
    if (g == 0) {
        float4 o = *(const float4*)(orig + (size_t)idx * 64 + l16 * 4);
        ushort4 v1 = *(const ushort4*)(h1 + (size_t)idx * 64 + l16 * 4);
        ushort4 v2 = *(const ushort4*)(h2 + (size_t)idx * 64 + l16 * 4);
        const float c3 = 1.0f / 3.0f;
        o.x += bf2f(v1.x) + 0.5f * bf2f(v2.x) + c3 * a.x;
        o.y += bf2f(v1.y) + 0.5f * bf2f(v2.y) + c3 * a.y;
        o.z += bf2f(v1.z) + 0.5f * bf2f(v2.z) + c3 * a.z;
        o.w += bf2f(v1.w) + 0.5f * bf2f(v2.w) + c3 * a.w;
        *(float4*)(out + (size_t)wave * 64 + l16 * 4) = o;
    }
}

extern "C" void kernel_launch(void* const* d_in, const int* in_sizes, int n_in,
                              void* d_out, int out_size, void* d_ws, size_t ws_size,
                              hipStream_t stream) {
    const float* user_feat = (const float*)d_in[0];
    const float* item_feat = (const float*)d_in[1];
    const int* edge_u = (const int*)d_in[2];
    const int* edge_i = (const int*)d_in[3];
    const int* users  = (const int*)d_in[4];
    const int* pos    = (const int*)d_in[5];
    const int* neg    = (const int*)d_in[6];
    float* out = (float*)d_out;

    const int D = 64;
    const int NU = in_sizes[0] / D;
    const int NI = in_sizes[1] / D;
    const int E  = in_sizes[2];
    const int B  = in_sizes[4];
    const int NT = NU + NI;

    char* ws = (char*)d_ws;
    size_t off = 0;
    auto alloc = [&](size_t bytes) -> void* {
        void* p = ws + off;
        off += bytes;
        off = (off + 255) & ~(size_t)255;
        return p;
    };
    // Zero zone: deg (NT) + total (1), contiguous for one memset.
    size_t zbytes = (size_t)(NT + 1) * 4;
    char* zbase = (char*)alloc(zbytes);
    int* deg   = (int*)zbase;
    int* total = deg + NT;
    int* offs   = (int*)alloc((size_t)NT * 4);
    int* cursor = (int*)alloc((size_t)NT * 4);
    int* csr    = (int*)alloc((size_t)2 * E * 4);
    unsigned short* ufb = (unsigned short*)alloc((size_t)NU * D * 2);
    unsigned short* ifb = (unsigned short*)alloc((size_t)NI * D * 2);
    unsigned short* uhA = (unsigned short*)alloc((size_t)NU * D * 2);
    unsigned short* ihA = (unsigned short*)alloc((size_t)NI * D * 2);
    unsigned short* uhB = (unsigned short*)alloc((size_t)NU * D * 2);
    unsigned short* ihB = (unsigned short*)alloc((size_t)NI * D * 2);

    hipMemsetAsync(zbase, 0, zbytes, stream);

    const int tb = 256;
    int n4u = NU * D / 4, n4i = NI * D / 4;
    conv_bf16_kernel<<<(n4u + tb - 1) / tb, tb, 0, stream>>>(user_feat, ufb, n4u);
    conv_bf16_kernel<<<(n4i + tb - 1) / tb, tb, 0, stream>>>(item_feat, ifb, n4i);

    int ethreads = (E + 1) / 2;
    count_deg_kernel<<<(ethreads + tb - 1) / tb, tb, 0, stream>>>(edge_u, edge_i, deg, E, NU);
    bump_kernel<<<(NT + tb - 1) / tb, tb, 0, stream>>>(deg, offs, cursor, total, NT);
    fill_csr_kernel<<<(ethreads + tb - 1) / tb, tb, 0, stream>>>(edge_u, edge_i, cursor,
                                                                 csr, E, NU);

    // Layer 1 and 2 full props; layer 3 fused into the epilogue.
    prop_both_kernel<<<(NT + 3) / 4, tb, 0, stream>>>(ufb, ifb, uhA, ihA,
                                                      offs, deg, csr, NU, NT);
    prop_both_kernel<<<(NT + 3) / 4, tb, 0, stream>>>(uhA, ihA, uhB, ihB,
                                                      offs, deg, csr, NU, NT);
    final_kernel<<<(3 * B + 3) / 4, tb, 0, stream>>>(
        user_feat, item_feat, uhA, ihA, uhB, ihB,
        users, pos, neg, offs, deg, csr, out, NU, B);
}

// Round 6
// 786.528 us; speedup vs baseline: 1.2293x; 1.2293x over previous
//
#include <hip/hip_runtime.h>
#include <math.h>

// LightGCN propagation, round 6 (isolation build).
// - Gather structure identical to rounds 2-4 (proven): per-group broadcast
//   CSR reads, explicit f32 edge weight, 4 groups x unroll 2 = 8 chains.
// - CSR entries are int2 {src_idx, weight_bits}: weight precomputed in fill
//   from isd[] (removes the deg[src] link from the gather dependency chain).
// - fill: one thread per (edge,direction) -> one atomic + one 8B store.
// - bf16 features/intermediates; layer 3 fused into the sampled-row epilogue.

__device__ __forceinline__ unsigned short f2bf(float f) {
    unsigned int b = __float_as_uint(f);
    b += 0x7FFFu + ((b >> 16) & 1u);          // round-to-nearest-even
    return (unsigned short)(b >> 16);
}
__device__ __forceinline__ float bf2f(unsigned short u) {
    return __uint_as_float(((unsigned int)u) << 16);
}

__global__ void count_deg_kernel(const int* __restrict__ eu, const int* __restrict__ ei,
                                 int* __restrict__ deg, int E, int NU) {
    int e = blockIdx.x * blockDim.x + threadIdx.x;
    if (e >= E) return;
    atomicAdd(&deg[eu[e]], 1);
    atomicAdd(&deg[NU + ei[e]], 1);
}

__global__ void bump_kernel(const int* __restrict__ deg, int* __restrict__ offs,
                            int* __restrict__ cursor, float* __restrict__ isd,
                            int* __restrict__ total, int n) {
    int i = blockIdx.x * blockDim.x + threadIdx.x;
    if (i >= n) return;
    int d = deg[i];
    int o = atomicAdd(total, d);        // bump alloc; row order irrelevant
    offs[i] = o;
    cursor[i] = o;                      // fill uses cursor directly
    isd[i] = d > 0 ? rsqrtf((float)d) : 0.f;
}

__global__ void conv_bf16_kernel(const float* __restrict__ src,
                                 unsigned short* __restrict__ dst, int n4) {
    int t = blockIdx.x * blockDim.x + threadIdx.x;
    if (t >= n4) return;
    float4 f = ((const float4*)src)[t];
    ushort4 o;
    o.x = f2bf(f.x); o.y = f2bf(f.y); o.z = f2bf(f.z); o.w = f2bf(f.w);
    ((ushort4*)dst)[t] = o;
}

// One thread per CSR entry: one atomic + one 8B store; weight precomputed.
__global__ void fill_csr_kernel(const int* __restrict__ eu, const int* __restrict__ ei,
                                const float* __restrict__ isd,
                                int* __restrict__ cursor, int2* __restrict__ csr,
                                int E, int NU) {
    int t = blockIdx.x * blockDim.x + threadIdx.x;
    if (t < E) {
        int u = eu[t], v = ei[t];
        float w = isd[u] * isd[NU + v];
        csr[atomicAdd(&cursor[u], 1)] = make_int2(v, __float_as_int(w));
    } else if (t < 2 * E) {
        int e = t - E;
        int u = eu[e], v = ei[e];
        float w = isd[u] * isd[NU + v];
        csr[atomicAdd(&cursor[NU + v], 1)] = make_int2(u, __float_as_int(w));
    }
}

// l2-normalized weighted sum for one dest row (rounds 2-4 proven structure).
// 4 groups of 16 lanes walk 4 interleaved edge streams, unroll x2.
__device__ __forceinline__ float4 gather_row(const unsigned short* __restrict__ sfeat,
                                             const int2* __restrict__ csr,
                                             int start, int dcount, int g, int l16) {
    float4 a0 = make_float4(0.f, 0.f, 0.f, 0.f);
    float4 a1 = make_float4(0.f, 0.f, 0.f, 0.f);
    int j = g;
    for (; j + 4 < dcount; j += 8) {
        int2 e0 = csr[start + j];
        int2 e1 = csr[start + j + 4];
        float w0 = __int_as_float(e0.y);
        float w1 = __int_as_float(e1.y);
        ushort4 f0 = *(const ushort4*)(sfeat + (size_t)e0.x * 64 + l16 * 4);
        ushort4 f1 = *(const ushort4*)(sfeat + (size_t)e1.x * 64 + l16 * 4);
        a0.x = fmaf(w0, bf2f(f0.x), a0.x); a0.y = fmaf(w0, bf2f(f0.y), a0.y);
        a0.z = fmaf(w0, bf2f(f0.z), a0.z); a0.w = fmaf(w0, bf2f(f0.w), a0.w);
        a1.x = fmaf(w1, bf2f(f1.x), a1.x); a1.y = fmaf(w1, bf2f(f1.y), a1.y);
        a1.z = fmaf(w1, bf2f(f1.z), a1.z); a1.w = fmaf(w1, bf2f(f1.w), a1.w);
    }
    if (j < dcount) {
        int2 e0 = csr[start + j];
        float w0 = __int_as_float(e0.y);
        ushort4 f0 = *(const ushort4*)(sfeat + (size_t)e0.x * 64 + l16 * 4);
        a0.x = fmaf(w0, bf2f(f0.x), a0.x); a0.y = fmaf(w0, bf2f(f0.y), a0.y);
        a0.z = fmaf(w0, bf2f(f0.z), a0.z); a0.w = fmaf(w0, bf2f(f0.w), a0.w);
    }
    float4 a = make_float4(a0.x + a1.x, a0.y + a1.y, a0.z + a1.z, a0.w + a1.w);
    #pragma unroll
    for (int m = 16; m <= 32; m <<= 1) {
        a.x += __shfl_xor(a.x, m, 64);
        a.y += __shfl_xor(a.y, m, 64);
        a.z += __shfl_xor(a.z, m, 64);
        a.w += __shfl_xor(a.w, m, 64);
    }
    float ss = a.x * a.x + a.y * a.y + a.z * a.z + a.w * a.w;
    #pragma unroll
    for (int m = 1; m <= 8; m <<= 1) ss += __shfl_xor(ss, m, 64);
    float scale = 1.f / fmaxf(sqrtf(ss), 1e-12f);
    a.x *= scale; a.y *= scale; a.z *= scale; a.w *= scale;
    return a;
}

// Rows [0,NU): users (gather from items); [NU,NT): items (from users).
__global__ void prop_both_kernel(const unsigned short* __restrict__ uc,
                                 const unsigned short* __restrict__ ic,
                                 unsigned short* __restrict__ ud,
                                 unsigned short* __restrict__ id,
                                 const int* __restrict__ offs, const int* __restrict__ deg,
                                 const int2* __restrict__ csr, int NU, int NT) {
    int wave = blockIdx.x * (blockDim.x >> 6) + (threadIdx.x >> 6);
    if (wave >= NT) return;
    int lane = threadIdx.x & 63;
    int g = lane >> 4, l16 = lane & 15;
    int r = __builtin_amdgcn_readfirstlane(wave);
    const unsigned short* sfeat;
    unsigned short* dst;
    if (r < NU) { sfeat = ic; dst = ud + (size_t)r * 64; }
    else        { sfeat = uc; dst = id + (size_t)(r - NU) * 64; }
    int start  = __builtin_amdgcn_readfirstlane(offs[r]);
    int dcount = __builtin_amdgcn_readfirstlane(deg[r]);
    float4 a = gather_row(sfeat, csr, start, dcount, g, l16);
    if (g == 0) {
        ushort4 o;
        o.x = f2bf(a.x); o.y = f2bf(a.y); o.z = f2bf(a.z); o.w = f2bf(a.w);
        *(ushort4*)(dst + l16 * 4) = o;
    }
}

// Fused epilogue: out = orig + h1 + 0.5*h2 + (1/3)*l2norm(layer-3 gather).
__global__ void final_kernel(const float* __restrict__ user_feat,
                             const float* __restrict__ item_feat,
                             const unsigned short* __restrict__ uhA,
                             const unsigned short* __restrict__ ihA,
                             const unsigned short* __restrict__ uhB,
                             const unsigned short* __restrict__ ihB,
                             const int* __restrict__ users, const int* __restrict__ pos,
                             const int* __restrict__ neg,
                             const int* __restrict__ offs, const int* __restrict__ deg,
                             const int2* __restrict__ csr, float* __restrict__ out,
                             int NU, int B) {
    int wave = blockIdx.x * (blockDim.x >> 6) + (threadIdx.x >> 6);
    if (wave >= 3 * B) return;
    int lane = threadIdx.x & 63;
    int g = lane >> 4, l16 = lane & 15;
    int seg = wave / B, b = wave - seg * B;
    int r, idx;
    const unsigned short *sfeat, *h1, *h2;
    const float* orig;
    if (seg == 0) {
        idx = users[b]; r = idx;
        sfeat = ihB; orig = user_feat; h1 = uhA; h2 = uhB;
    } else {
        idx = (seg == 1) ? pos[b] : neg[b];
        r = NU + idx;
        sfeat = uhB; orig = item_feat; h1 = ihA; h2 = ihB;
    }
    r = __builtin_amdgcn_readfirstlane(r);
    int start  = __builtin_amdgcn_readfirstlane(offs[r]);
    int dcount = __builtin_amdgcn_readfirstlane(deg[r]);
    float4 a = gather_row(sfeat, csr, start, dcount, g, l16);
    if (g == 0) {
        float4 o = *(const float4*)(orig + (size_t)idx * 64 + l16 * 4);
        ushort4 v1 = *(const ushort4*)(h1 + (size_t)idx * 64 + l16 * 4);
        ushort4 v2 = *(const ushort4*)(h2 + (size_t)idx * 64 + l16 * 4);
        const float c3 = 1.0f / 3.0f;
        o.x += bf2f(v1.x) + 0.5f * bf2f(v2.x) + c3 * a.x;
        o.y += bf2f(v1.y) + 0.5f * bf2f(v2.y) + c3 * a.y;
        o.z += bf2f(v1.z) + 0.5f * bf2f(v2.z) + c3 * a.z;
        o.w += bf2f(v1.w) + 0.5f * bf2f(v2.w) + c3 * a.w;
        *(float4*)(out + (size_t)wave * 64 + l16 * 4) = o;
    }
}

extern "C" void kernel_launch(void* const* d_in, const int* in_sizes, int n_in,
                              void* d_out, int out_size, void* d_ws, size_t ws_size,
                              hipStream_t stream) {
    const float* user_feat = (const float*)d_in[0];
    const float* item_feat = (const float*)d_in[1];
    const int* edge_u = (const int*)d_in[2];
    const int* edge_i = (const int*)d_in[3];
    const int* users  = (const int*)d_in[4];
    const int* pos    = (const int*)d_in[5];
    const int* neg    = (const int*)d_in[6];
    float* out = (float*)d_out;

    const int D = 64;
    const int NU = in_sizes[0] / D;
    const int NI = in_sizes[1] / D;
    const int E  = in_sizes[2];
    const int B  = in_sizes[4];
    const int NT = NU + NI;

    char* ws = (char*)d_ws;
    size_t off = 0;
    auto alloc = [&](size_t bytes) -> void* {
        void* p = ws + off;
        off += bytes;
        off = (off + 255) & ~(size_t)255;
        return p;
    };
    // Zero zone: deg (NT) + total (1), contiguous for one memset.
    size_t zbytes = (size_t)(NT + 1) * 4;
    char* zbase = (char*)alloc(zbytes);
    int* deg   = (int*)zbase;
    int* total = deg + NT;
    int*   offs   = (int*)alloc((size_t)NT * 4);
    int*   cursor = (int*)alloc((size_t)NT * 4);
    float* isd    = (float*)alloc((size_t)NT * 4);
    int2*  csr    = (int2*)alloc((size_t)2 * E * 8);
    unsigned short* ufb = (unsigned short*)alloc((size_t)NU * D * 2);
    unsigned short* ifb = (unsigned short*)alloc((size_t)NI * D * 2);
    unsigned short* uhA = (unsigned short*)alloc((size_t)NU * D * 2);
    unsigned short* ihA = (unsigned short*)alloc((size_t)NI * D * 2);
    unsigned short* uhB = (unsigned short*)alloc((size_t)NU * D * 2);
    unsigned short* ihB = (unsigned short*)alloc((size_t)NI * D * 2);

    hipMemsetAsync(zbase, 0, zbytes, stream);

    const int tb = 256;
    count_deg_kernel<<<(E + tb - 1) / tb, tb, 0, stream>>>(edge_u, edge_i, deg, E, NU);
    bump_kernel<<<(NT + tb - 1) / tb, tb, 0, stream>>>(deg, offs, cursor, isd, total, NT);

    int n4u = NU * D / 4, n4i = NI * D / 4;
    conv_bf16_kernel<<<(n4u + tb - 1) / tb, tb, 0, stream>>>(user_feat, ufb, n4u);
    conv_bf16_kernel<<<(n4i + tb - 1) / tb, tb, 0, stream>>>(item_feat, ifb, n4i);

    fill_csr_kernel<<<(2 * E + tb - 1) / tb, tb, 0, stream>>>(edge_u, edge_i, isd,
                                                              cursor, csr, E, NU);

    // Layers 1,2 full props; layer 3 fused into the epilogue.
    prop_both_kernel<<<(NT + 3) / 4, tb, 0, stream>>>(ufb, ifb, uhA, ihA,
                                                      offs, deg, csr, NU, NT);
    prop_both_kernel<<<(NT + 3) / 4, tb, 0, stream>>>(uhA, ihA, uhB, ihB,
                                                      offs, deg, csr, NU, NT);
    final_kernel<<<(3 * B + 3) / 4, tb, 0, stream>>>(
        user_feat, item_feat, uhA, ihA, uhB, ihB,
        users, pos, neg, offs, deg, csr, out, NU, B);
}

// Round 7
// 704.060 us; speedup vs baseline: 1.3732x; 1.1171x over previous
//
#include <hip/hip_runtime.h>
#include <math.h>

// LightGCN propagation, round 7.
// Change vs r6 (isolated): gather restructured to 16-lanes-per-row,
// 4 rows per wave, unroll x4 => 16 independent 128B gathers in flight
// per wave (vs 2-4). Reduction stays within each 16-lane group.
// CSR build (count/bump/fill int2{src,w}) identical to round 6 (proven).

__device__ __forceinline__ unsigned short f2bf(float f) {
    unsigned int b = __float_as_uint(f);
    b += 0x7FFFu + ((b >> 16) & 1u);          // round-to-nearest-even
    return (unsigned short)(b >> 16);
}
__device__ __forceinline__ float bf2f(unsigned short u) {
    return __uint_as_float(((unsigned int)u) << 16);
}

__global__ void count_deg_kernel(const int* __restrict__ eu, const int* __restrict__ ei,
                                 int* __restrict__ deg, int E, int NU) {
    int e = blockIdx.x * blockDim.x + threadIdx.x;
    if (e >= E) return;
    atomicAdd(&deg[eu[e]], 1);
    atomicAdd(&deg[NU + ei[e]], 1);
}

__global__ void bump_kernel(const int* __restrict__ deg, int* __restrict__ offs,
                            int* __restrict__ cursor, float* __restrict__ isd,
                            int* __restrict__ total, int n) {
    int i = blockIdx.x * blockDim.x + threadIdx.x;
    if (i >= n) return;
    int d = deg[i];
    int o = atomicAdd(total, d);        // bump alloc; row order irrelevant
    offs[i] = o;
    cursor[i] = o;                      // fill uses cursor directly
    isd[i] = d > 0 ? rsqrtf((float)d) : 0.f;
}

__global__ void conv_bf16_kernel(const float* __restrict__ src,
                                 unsigned short* __restrict__ dst, int n4) {
    int t = blockIdx.x * blockDim.x + threadIdx.x;
    if (t >= n4) return;
    float4 f = ((const float4*)src)[t];
    ushort4 o;
    o.x = f2bf(f.x); o.y = f2bf(f.y); o.z = f2bf(f.z); o.w = f2bf(f.w);
    ((ushort4*)dst)[t] = o;
}

// One thread per CSR entry: one atomic + one 8B store; weight precomputed.
__global__ void fill_csr_kernel(const int* __restrict__ eu, const int* __restrict__ ei,
                                const float* __restrict__ isd,
                                int* __restrict__ cursor, int2* __restrict__ csr,
                                int E, int NU) {
    int t = blockIdx.x * blockDim.x + threadIdx.x;
    if (t < E) {
        int u = eu[t], v = ei[t];
        float w = isd[u] * isd[NU + v];
        csr[atomicAdd(&cursor[u], 1)] = make_int2(v, __float_as_int(w));
    } else if (t < 2 * E) {
        int e = t - E;
        int u = eu[e], v = ei[e];
        float w = isd[u] * isd[NU + v];
        csr[atomicAdd(&cursor[NU + v], 1)] = make_int2(u, __float_as_int(w));
    }
}

// l2-normalized weighted sum for one dest row, computed by a 16-lane group.
// Unroll x4: 4 independent feat gathers in flight per group.
// Returns the normalized float4 slice (columns l16*4 .. +4) of the row.
__device__ __forceinline__ float4 gather16(const unsigned short* __restrict__ sfeat,
                                           const int2* __restrict__ csr,
                                           int start, int dcount, int l16) {
    float4 a0 = make_float4(0.f, 0.f, 0.f, 0.f);
    float4 a1 = make_float4(0.f, 0.f, 0.f, 0.f);
    float4 a2 = make_float4(0.f, 0.f, 0.f, 0.f);
    float4 a3 = make_float4(0.f, 0.f, 0.f, 0.f);
    int j = 0;
    for (; j + 3 < dcount; j += 4) {
        int2 e0 = csr[start + j];
        int2 e1 = csr[start + j + 1];
        int2 e2 = csr[start + j + 2];
        int2 e3 = csr[start + j + 3];
        ushort4 f0 = *(const ushort4*)(sfeat + (size_t)e0.x * 64 + l16 * 4);
        ushort4 f1 = *(const ushort4*)(sfeat + (size_t)e1.x * 64 + l16 * 4);
        ushort4 f2 = *(const ushort4*)(sfeat + (size_t)e2.x * 64 + l16 * 4);
        ushort4 f3 = *(const ushort4*)(sfeat + (size_t)e3.x * 64 + l16 * 4);
        float w0 = __int_as_float(e0.y), w1 = __int_as_float(e1.y);
        float w2 = __int_as_float(e2.y), w3 = __int_as_float(e3.y);
        a0.x = fmaf(w0, bf2f(f0.x), a0.x); a0.y = fmaf(w0, bf2f(f0.y), a0.y);
        a0.z = fmaf(w0, bf2f(f0.z), a0.z); a0.w = fmaf(w0, bf2f(f0.w), a0.w);
        a1.x = fmaf(w1, bf2f(f1.x), a1.x); a1.y = fmaf(w1, bf2f(f1.y), a1.y);
        a1.z = fmaf(w1, bf2f(f1.z), a1.z); a1.w = fmaf(w1, bf2f(f1.w), a1.w);
        a2.x = fmaf(w2, bf2f(f2.x), a2.x); a2.y = fmaf(w2, bf2f(f2.y), a2.y);
        a2.z = fmaf(w2, bf2f(f2.z), a2.z); a2.w = fmaf(w2, bf2f(f2.w), a2.w);
        a3.x = fmaf(w3, bf2f(f3.x), a3.x); a3.y = fmaf(w3, bf2f(f3.y), a3.y);
        a3.z = fmaf(w3, bf2f(f3.z), a3.z); a3.w = fmaf(w3, bf2f(f3.w), a3.w);
    }
    for (; j < dcount; ++j) {
        int2 e0 = csr[start + j];
        float w0 = __int_as_float(e0.y);
        ushort4 f0 = *(const ushort4*)(sfeat + (size_t)e0.x * 64 + l16 * 4);
        a0.x = fmaf(w0, bf2f(f0.x), a0.x); a0.y = fmaf(w0, bf2f(f0.y), a0.y);
        a0.z = fmaf(w0, bf2f(f0.z), a0.z); a0.w = fmaf(w0, bf2f(f0.w), a0.w);
    }
    float4 a = make_float4(a0.x + a1.x + a2.x + a3.x,
                           a0.y + a1.y + a2.y + a3.y,
                           a0.z + a1.z + a2.z + a3.z,
                           a0.w + a1.w + a2.w + a3.w);
    float ss = a.x * a.x + a.y * a.y + a.z * a.z + a.w * a.w;
    #pragma unroll
    for (int m = 1; m <= 8; m <<= 1) ss += __shfl_xor(ss, m, 64);  // within 16-lane group
    float scale = 1.f / fmaxf(sqrtf(ss), 1e-12f);
    a.x *= scale; a.y *= scale; a.z *= scale; a.w *= scale;
    return a;
}

// 4 rows per wave (one per 16-lane group). Rows [0,NU): users (gather from
// items); [NU,NT): items (gather from users).
__global__ void prop_both_kernel(const unsigned short* __restrict__ uc,
                                 const unsigned short* __restrict__ ic,
                                 unsigned short* __restrict__ ud,
                                 unsigned short* __restrict__ id,
                                 const int* __restrict__ offs, const int* __restrict__ deg,
                                 const int2* __restrict__ csr, int NU, int NT) {
    int t = blockIdx.x * blockDim.x + threadIdx.x;
    int r = t >> 4;                 // global 16-lane group id = row
    if (r >= NT) return;
    int l16 = t & 15;
    const unsigned short* sfeat;
    unsigned short* dst;
    if (r < NU) { sfeat = ic; dst = ud + (size_t)r * 64; }
    else        { sfeat = uc; dst = id + (size_t)(r - NU) * 64; }
    int start  = offs[r];
    int dcount = deg[r];
    float4 a = gather16(sfeat, csr, start, dcount, l16);
    ushort4 o;
    o.x = f2bf(a.x); o.y = f2bf(a.y); o.z = f2bf(a.z); o.w = f2bf(a.w);
    *(ushort4*)(dst + l16 * 4) = o;
}

// Fused epilogue at the 3*B sampled rows (4 samples per wave):
// out = orig + h1 + 0.5*h2 + (1/3)*l2norm(layer-3 gather).
__global__ void final_kernel(const float* __restrict__ user_feat,
                             const float* __restrict__ item_feat,
                             const unsigned short* __restrict__ uhA,
                             const unsigned short* __restrict__ ihA,
                             const unsigned short* __restrict__ uhB,
                             const unsigned short* __restrict__ ihB,
                             const int* __restrict__ users, const int* __restrict__ pos,
                             const int* __restrict__ neg,
                             const int* __restrict__ offs, const int* __restrict__ deg,
                             const int2* __restrict__ csr, float* __restrict__ out,
                             int NU, int B) {
    int t = blockIdx.x * blockDim.x + threadIdx.x;
    int s = t >> 4;                 // global sample id
    if (s >= 3 * B) return;
    int l16 = t & 15;
    int seg = s / B, b = s - seg * B;
    int r, idx;
    const unsigned short *sfeat, *h1, *h2;
    const float* orig;
    if (seg == 0) {
        idx = users[b]; r = idx;
        sfeat = ihB; orig = user_feat; h1 = uhA; h2 = uhB;
    } else {
        idx = (seg == 1) ? pos[b] : neg[b];
        r = NU + idx;
        sfeat = uhB; orig = item_feat; h1 = ihA; h2 = ihB;
    }
    int start  = offs[r];
    int dcount = deg[r];
    float4 a = gather16(sfeat, csr, start, dcount, l16);
    float4 o = *(const float4*)(orig + (size_t)idx * 64 + l16 * 4);
    ushort4 v1 = *(const ushort4*)(h1 + (size_t)idx * 64 + l16 * 4);
    ushort4 v2 = *(const ushort4*)(h2 + (size_t)idx * 64 + l16 * 4);
    const float c3 = 1.0f / 3.0f;
    o.x += bf2f(v1.x) + 0.5f * bf2f(v2.x) + c3 * a.x;
    o.y += bf2f(v1.y) + 0.5f * bf2f(v2.y) + c3 * a.y;
    o.z += bf2f(v1.z) + 0.5f * bf2f(v2.z) + c3 * a.z;
    o.w += bf2f(v1.w) + 0.5f * bf2f(v2.w) + c3 * a.w;
    *(float4*)(out + (size_t)s * 64 + l16 * 4) = o;
}

extern "C" void kernel_launch(void* const* d_in, const int* in_sizes, int n_in,
                              void* d_out, int out_size, void* d_ws, size_t ws_size,
                              hipStream_t stream) {
    const float* user_feat = (const float*)d_in[0];
    const float* item_feat = (const float*)d_in[1];
    const int* edge_u = (const int*)d_in[2];
    const int* edge_i = (const int*)d_in[3];
    const int* users  = (const int*)d_in[4];
    const int* pos    = (const int*)d_in[5];
    const int* neg    = (const int*)d_in[6];
    float* out = (float*)d_out;

    const int D = 64;
    const int NU = in_sizes[0] / D;
    const int NI = in_sizes[1] / D;
    const int E  = in_sizes[2];
    const int B  = in_sizes[4];
    const int NT = NU + NI;

    char* ws = (char*)d_ws;
    size_t off = 0;
    auto alloc = [&](size_t bytes) -> void* {
        void* p = ws + off;
        off += bytes;
        off = (off + 255) & ~(size_t)255;
        return p;
    };
    // Zero zone: deg (NT) + total (1), contiguous for one memset.
    size_t zbytes = (size_t)(NT + 1) * 4;
    char* zbase = (char*)alloc(zbytes);
    int* deg   = (int*)zbase;
    int* total = deg + NT;
    int*   offs   = (int*)alloc((size_t)NT * 4);
    int*   cursor = (int*)alloc((size_t)NT * 4);
    float* isd    = (float*)alloc((size_t)NT * 4);
    int2*  csr    = (int2*)alloc((size_t)2 * E * 8);
    unsigned short* ufb = (unsigned short*)alloc((size_t)NU * D * 2);
    unsigned short* ifb = (unsigned short*)alloc((size_t)NI * D * 2);
    unsigned short* uhA = (unsigned short*)alloc((size_t)NU * D * 2);
    unsigned short* ihA = (unsigned short*)alloc((size_t)NI * D * 2);
    unsigned short* uhB = (unsigned short*)alloc((size_t)NU * D * 2);
    unsigned short* ihB = (unsigned short*)alloc((size_t)NI * D * 2);

    hipMemsetAsync(zbase, 0, zbytes, stream);

    const int tb = 256;
    count_deg_kernel<<<(E + tb - 1) / tb, tb, 0, stream>>>(edge_u, edge_i, deg, E, NU);
    bump_kernel<<<(NT + tb - 1) / tb, tb, 0, stream>>>(deg, offs, cursor, isd, total, NT);

    int n4u = NU * D / 4, n4i = NI * D / 4;
    conv_bf16_kernel<<<(n4u + tb - 1) / tb, tb, 0, stream>>>(user_feat, ufb, n4u);
    conv_bf16_kernel<<<(n4i + tb - 1) / tb, tb, 0, stream>>>(item_feat, ifb, n4i);

    fill_csr_kernel<<<(2 * E + tb - 1) / tb, tb, 0, stream>>>(edge_u, edge_i, isd,
                                                              cursor, csr, E, NU);

    // Layers 1,2 full props (16 threads per row); layer 3 fused into epilogue.
    int pthreads = NT * 16;
    prop_both_kernel<<<(pthreads + tb - 1) / tb, tb, 0, stream>>>(
        ufb, ifb, uhA, ihA, offs, deg, csr, NU, NT);
    prop_both_kernel<<<(pthreads + tb - 1) / tb, tb, 0, stream>>>(
        uhA, ihA, uhB, ihB, offs, deg, csr, NU, NT);
    int fthreads = 3 * B * 16;
    final_kernel<<<(fthreads + tb - 1) / tb, tb, 0, stream>>>(
        user_feat, item_feat, uhA, ihA, uhB, ihB,
        users, pos, neg, offs, deg, csr, out, NU, B);
}